// Round 5
// baseline (736.263 us; speedup 1.0000x reference)
//
#include <hip/hip_runtime.h>
#include <hip/hip_bf16.h>

// PointNetConv on MI355X (gfx950) — round 12. f32 inputs.
// Algebra: h1 = relu(A[row] - P[col]),  A = x@W1x + b1 + pos@W1p,  P = pos@W1p.
//
// r11 post-mortem: packed-stream pernode REGRESSED (142 -> 176us): VGPR 132
// broke the 128 boundary (3 waves/SIMD, occupancy 19.6 -> 10.1), P re-fetched
// per chunk (was per-node register-resident), 16 shuffles per chunk (was per
// node). The f16 packed relu + u32 bucketing parts were sound.
//
// r12: r10's PROVEN 3-level CSR pernode structure x f16 packed relu x u32
// passA/passB. passB emits r10-format CSR (srow + start/end). pernode gets
// __launch_bounds__(256,4) to pin VGPR <= 128 (4 waves/SIMD).

typedef _Float16 f16_t;
typedef _Float16 f16x8 __attribute__((ext_vector_type(8)));
typedef float    f32x4 __attribute__((ext_vector_type(4)));

#define DPAD 16
#define NSB_SHIFT 8          // 256 nodes per superbucket
#define SBCAP 9216           // per-bucket edge cap (mean 8192, +11 sigma)
#define PA_TILE 2048         // edges per passA tile

__device__ __forceinline__ f16x8 sub_relu8(f16x8 a, f16x8 b) {
  f16x8 d = a - b;                          // v_pk_add_f16 (neg)
  f16x8 z = {};
  return __builtin_elementwise_max(d, z);   // v_pk_max_f16
}

// ---------------- fallback scan chain (proven r7) ----------------
__global__ __launch_bounds__(256) void tilesum_kernel(const int* __restrict__ dpad,
                                                      int* __restrict__ tsum, int N) {
  __shared__ int ws[4];
  int tid = threadIdx.x;
  int i = blockIdx.x * 256 + tid;
  int v = (i < N) ? dpad[(long)i * DPAD] : 0;
#pragma unroll
  for (int off = 32; off > 0; off >>= 1) v += __shfl_down(v, off, 64);
  if ((tid & 63) == 0) ws[tid >> 6] = v;
  __syncthreads();
  if (tid == 0) tsum[blockIdx.x] = ws[0] + ws[1] + ws[2] + ws[3];
}

__global__ __launch_bounds__(256) void tscan_kernel(const int* __restrict__ tsum,
                                                    int* __restrict__ texcl,
                                                    int* __restrict__ startN, int nt_) {
  __shared__ int wsum[4];
  int tid = threadIdx.x, lane = tid & 63, w = tid >> 6;
  int v = (tid < nt_) ? tsum[tid] : 0;
  int s = v;
#pragma unroll
  for (int off = 1; off < 64; off <<= 1) {
    int t = __shfl_up(s, off, 64);
    if (lane >= off) s += t;
  }
  if (lane == 63) wsum[w] = s;
  __syncthreads();
  int add = 0;
  for (int j = 0; j < w; ++j) add += wsum[j];
  if (tid < nt_) texcl[tid] = add + s - v;
  if (tid == 0) *startN = wsum[0] + wsum[1] + wsum[2] + wsum[3];
}

__global__ __launch_bounds__(256) void scanout_kernel(int* __restrict__ dpad,
                                                      const int* __restrict__ texcl,
                                                      int* __restrict__ start, int N) {
  __shared__ int wsum[4];
  int tid = threadIdx.x, lane = tid & 63, w = tid >> 6;
  int i = blockIdx.x * 256 + tid;
  int v = (i < N) ? dpad[(long)i * DPAD] : 0;
  int s = v;
#pragma unroll
  for (int off = 1; off < 64; off <<= 1) {
    int t = __shfl_up(s, off, 64);
    if (lane >= off) s += t;
  }
  if (lane == 63) wsum[w] = s;
  __syncthreads();
  int add = texcl[blockIdx.x];
  for (int j = 0; j < w; ++j) add += wsum[j];
  int excl = add + s - v;
  if (i < N) { start[i] = excl; dpad[(long)i * DPAD + 8] = excl; }
}

__global__ __launch_bounds__(256) void scatter_kernel(const int* __restrict__ eidx,
                                                      int* __restrict__ dpad,
                                                      int* __restrict__ srow, int E) {
  int i = blockIdx.x * 256 + threadIdx.x;
  if (i < E) {
    int slot = atomicAdd(&dpad[(long)eidx[E + i] * DPAD + 8], 1);
    srow[slot] = eidx[i];
  }
}

__device__ __forceinline__ f16x8 load_frag8h(const float* p) {
  float4 a = *(const float4*)p;
  float4 b = *(const float4*)(p + 4);
  f16x8 r;
  r[0] = (f16_t)a.x; r[1] = (f16_t)a.y; r[2] = (f16_t)a.z; r[3] = (f16_t)a.w;
  r[4] = (f16_t)b.x; r[5] = (f16_t)b.y; r[6] = (f16_t)b.z; r[7] = (f16_t)b.w;
  return r;
}

// ---------------------------------------------------------------------------
// Shared-memory structs for the role-split kernels (union via char buffer).
// ---------------------------------------------------------------------------
struct GemmSmem {
  f16_t ws_[8][4][64][8];    // 32768 B
  float w1ps[3][128];        //  1536 B
  float bs_[128];            //   512 B
  float pos_s[64][3];        //   768 B
};                           // 35584 B

struct PassASmem {
  unsigned sorted[PA_TILE];       // 8192 B
  unsigned char sbb[PA_TILE];     // 2048 B
  int hist[256];
  int off_[256];
  int cur[256];
  int gbase[256];
  int scanb[256];
};                                // 15360 B

#define SMEM_BYTES 35840

// ---------------------------------------------------------------------------
// AP-GEMM body: A = x@W1x + b1 + pos@W1p, P = pos@W1p (f16 into d_out).
// ---------------------------------------------------------------------------
__device__ __forceinline__ void ap_gemm_body(
    const float* __restrict__ x, const float* __restrict__ pos,
    const float* __restrict__ W1, const float* __restrict__ b1,
    f16_t* __restrict__ Abuf, f16_t* __restrict__ Pbuf, int N, int blk,
    char* smem)
{
  GemmSmem* G = (GemmSmem*)smem;
  const int tid = threadIdx.x;
  for (int it = tid; it < 8 * 4 * 64; it += 256) {
    int nt = it >> 8, kt = (it >> 6) & 3, l = it & 63;
    int n = nt * 16 + (l & 15), quad = l >> 4;
    f16x8 v;
#pragma unroll
    for (int j = 0; j < 8; ++j) v[j] = (f16_t)W1[(kt * 32 + quad * 8 + j) * 128 + n];
    *(f16x8*)&G->ws_[nt][kt][l][0] = v;
  }
  for (int it = tid; it < 384; it += 256)
    G->w1ps[it >> 7][it & 127] = W1[(128 + (it >> 7)) * 128 + (it & 127)];
  if (tid < 128) G->bs_[tid] = b1[tid];
  {
    int g = blk * 192 + tid;
    if (tid < 192 && g < 3 * N) G->pos_s[tid / 3][tid % 3] = pos[g];
  }
  __syncthreads();

  const int w = tid >> 6, lane = tid & 63;
  const int m15 = lane & 15, quad = lane >> 4;

  int node_a = blk * 64 + w * 16 + m15;
  const float* xrow = x + (long)min(node_a, N - 1) * 128;
  f16x8 a[4];
#pragma unroll
  for (int kt = 0; kt < 4; ++kt)
    a[kt] = load_frag8h(xrow + kt * 32 + quad * 8);

  f32x4 acc[8];
#pragma unroll
  for (int nt = 0; nt < 8; ++nt) acc[nt] = (f32x4){0.f, 0.f, 0.f, 0.f};
#pragma unroll
  for (int nt = 0; nt < 8; ++nt)
#pragma unroll
    for (int kt = 0; kt < 4; ++kt)
      acc[nt] = __builtin_amdgcn_mfma_f32_16x16x32_f16(
          a[kt], *(const f16x8*)&G->ws_[nt][kt][lane][0], acc[nt], 0, 0, 0);

#pragma unroll
  for (int r = 0; r < 4; ++r) {
    int nl = w * 16 + quad * 4 + r;
    int node = blk * 64 + nl;
    if (node < N) {
      float p0 = G->pos_s[nl][0], p1 = G->pos_s[nl][1], p2 = G->pos_s[nl][2];
#pragma unroll
      for (int nt = 0; nt < 8; ++nt) {
        int c = nt * 16 + m15;
        float pv = p0 * G->w1ps[0][c] + p1 * G->w1ps[1][c] + p2 * G->w1ps[2][c];
        long idx = (long)node * 128 + c;
        Abuf[idx] = (f16_t)(acc[nt][r] + G->bs_[c] + pv);
        Pbuf[idx] = (f16_t)pv;
      }
    }
  }
}

// ---------------------------------------------------------------------------
// passA body: tile-sort PA_TILE edges into superbuckets, all random ops in
// LDS; ~NSB aggregated global atomics per tile; coalesced u32 segment writes.
// Entry format: (col&255)<<24 | row.
// ---------------------------------------------------------------------------
__device__ __forceinline__ void passa_body(
    const int* __restrict__ eidx, unsigned* __restrict__ pairsBuf,
    int* __restrict__ superCursor, int E, int tile, char* smem)
{
  PassASmem* S = (PassASmem*)smem;
  const int tid = threadIdx.x;
  const int base = tile * PA_TILE;
  const int cnt_t = min(PA_TILE, E - base);

  for (int j = tid; j < 256; j += 256) S->hist[j] = 0;
  __syncthreads();

  int myrow[8], mycol[8];
#pragma unroll
  for (int k = 0; k < 8; ++k) {
    int idx = k * 256 + tid;
    int i = base + idx;
    if (idx < cnt_t) {
      myrow[k] = eidx[i];
      mycol[k] = eidx[E + i];
      atomicAdd(&S->hist[mycol[k] >> NSB_SHIFT], 1);
    } else mycol[k] = -1;
  }
  __syncthreads();

  int v = S->hist[tid];
  S->scanb[tid] = v;
  __syncthreads();
  for (int d = 1; d < 256; d <<= 1) {
    int t = (tid >= d) ? S->scanb[tid - d] : 0;
    __syncthreads();
    S->scanb[tid] += t;
    __syncthreads();
  }
  int excl = S->scanb[tid] - v;
  S->off_[tid] = excl;
  S->cur[tid]  = excl;
  S->gbase[tid] = (v > 0) ? atomicAdd(&superCursor[tid * 16], v) : 0;
  __syncthreads();

#pragma unroll
  for (int k = 0; k < 8; ++k) {
    if (mycol[k] >= 0) {
      int sb = mycol[k] >> NSB_SHIFT;
      int pos = atomicAdd(&S->cur[sb], 1);
      S->sorted[pos] = ((unsigned)(mycol[k] & 255) << 24) | (unsigned)myrow[k];
      S->sbb[pos] = (unsigned char)sb;
    }
  }
  __syncthreads();

#pragma unroll
  for (int k = 0; k < 8; ++k) {
    int idx = k * 256 + tid;
    if (idx < cnt_t) {
      int sb = S->sbb[idx];
      int local = idx - S->off_[sb];
      int g = S->gbase[sb] + local;
      if (g < SBCAP) pairsBuf[(long)sb * SBCAP + g] = S->sorted[idx];
    }
  }
}

// fusedA: AP-GEMM role + passA role in one launch (overlap).
__global__ __launch_bounds__(256) void fusedA_kernel(
    const float* __restrict__ x, const float* __restrict__ pos,
    const int* __restrict__ eidx, const float* __restrict__ W1,
    const float* __restrict__ b1, unsigned* __restrict__ pairsBuf,
    int* __restrict__ superCursor, f16_t* __restrict__ Abuf,
    f16_t* __restrict__ Pbuf, int N, int E, int nodeBlocks)
{
  __shared__ __align__(16) char smem[SMEM_BYTES];
  if ((int)blockIdx.x >= nodeBlocks) {
    passa_body(eidx, pairsBuf, superCursor, E, (int)blockIdx.x - nodeBlocks, smem);
    return;
  }
  ap_gemm_body(x, pos, W1, b1, Abuf, Pbuf, N, blockIdx.x, smem);
}

// Fallback path: hist role + AP-GEMM role (r7-proven).
__global__ __launch_bounds__(256) void fused_hist_kernel(
    const float* __restrict__ x, const float* __restrict__ pos,
    const int* __restrict__ eidx, const float* __restrict__ W1,
    const float* __restrict__ b1, int* __restrict__ dpad,
    f16_t* __restrict__ Abuf, f16_t* __restrict__ Pbuf,
    int N, int E, int nodeBlocks)
{
  __shared__ __align__(16) char smem[SMEM_BYTES];
  if ((int)blockIdx.x >= nodeBlocks) {
    int i = ((int)blockIdx.x - nodeBlocks) * 256 + threadIdx.x;
    if (i < E) atomicAdd(&dpad[(long)eidx[E + i] * DPAD], 1);
    return;
  }
  ap_gemm_body(x, pos, W1, b1, Abuf, Pbuf, N, blockIdx.x, smem);
}

// ---------------------------------------------------------------------------
// passB: one block per superbucket; exact per-node CSR built in LDS from u32
// pairs. Emits r10-format CSR: srow (row indices), startB[n], endB[n].
// ---------------------------------------------------------------------------
__global__ __launch_bounds__(256) void passb_kernel(
    const unsigned* __restrict__ pairsA, const int* __restrict__ superCursor,
    int* __restrict__ srow, int* __restrict__ startB, int* __restrict__ endB,
    int N)
{
  __shared__ int rows[SBCAP];     // 36 KB
  __shared__ int deg[256], scanb[256], cur[256];
  const int sb = blockIdx.x, tid = threadIdx.x;
  const int cntIn = min(superCursor[sb * 16], SBCAP);
  const unsigned* Pin = pairsA + (long)sb * SBCAP;

  deg[tid] = 0;
  __syncthreads();
  for (int i = tid; i < cntIn; i += 256)
    atomicAdd(&deg[Pin[i] >> 24], 1);
  __syncthreads();
  int d = deg[tid];
  scanb[tid] = d;
  __syncthreads();
  for (int s = 1; s < 256; s <<= 1) {
    int t2 = (tid >= s) ? scanb[tid - s] : 0;
    __syncthreads();
    scanb[tid] += t2;
    __syncthreads();
  }
  int excl = scanb[tid] - d;
  cur[tid] = excl;
  int n = (sb << NSB_SHIFT) + tid;
  if (n < N) {
    startB[n] = sb * SBCAP + excl;
    endB[n]   = sb * SBCAP + excl + d;
  }
  __syncthreads();
  for (int i = tid; i < cntIn; i += 256) {
    unsigned p = Pin[i];
    int slot = atomicAdd(&cur[p >> 24], 1);
    rows[slot] = (int)(p & 0xFFFFFFu);
  }
  __syncthreads();
  const int gb = sb * SBCAP;
  for (int i = tid; i < cntIn; i += 256) srow[gb + i] = rows[i];
}

// ---------------------------------------------------------------------------
// pernode (r10-proven structure, f16 packed): continuous (node,chunk) stream
// per wave over a contiguous node range; 3-level pipeline crossing node
// boundaries (srow 2 ahead, A-gather + next-node P 1 ahead, compute level-0).
// __launch_bounds__(256,4) pins VGPR <= 128 -> 4 waves/SIMD.
// ---------------------------------------------------------------------------
__global__ __launch_bounds__(256, 4) void pernode_kernel(
    const f16_t* __restrict__ Abuf, const f16_t* __restrict__ Pbuf,
    const float* __restrict__ W2, const float* __restrict__ b2,
    const int* __restrict__ startp, const int* __restrict__ endp,
    const int* __restrict__ srow, f16_t* __restrict__ maxbf, int N)
{
  __shared__ f16_t w2s[8][4][64][8];   // 32 KB, B-fragment-major
  __shared__ float b2s[128];

  const int tid = threadIdx.x;
  for (int it = tid; it < 8 * 4 * 64; it += 256) {
    int nt = it >> 8, kt = (it >> 6) & 3, l = it & 63;
    int ncol = nt * 16 + (l & 15), q = l >> 4;
    f16x8 v;
#pragma unroll
    for (int j = 0; j < 8; ++j) v[j] = (f16_t)W2[(kt * 32 + q * 8 + j) * 128 + ncol];
    *(f16x8*)&w2s[nt][kt][l][0] = v;
  }
  if (tid < 128) b2s[tid] = b2[tid];
  __syncthreads();

  const int w = tid >> 6, lane = tid & 63;
  const int m15 = lane & 15, quad = lane >> 4;

  const int nslots = (int)gridDim.x * 4;
  const int slot   = (int)blockIdx.x * 4 + w;
  const int K      = (N + nslots - 1) / nslots;
  const int nBeg   = slot * K;
  const int nEnd   = min(N, nBeg + K);
  if (nBeg >= nEnd) return;

  auto adv = [&](int& n, int& c, int& e) {
    c += 16;
    if (c < e) return;
    for (;;) {
      if (++n >= nEnd) { n = nEnd; c -= 16; return; }
      int s_ = startp[n], e_ = endp[n];
      if (e_ > s_) { c = s_; e = e_; return; }
      if (quad == 0) {
#pragma unroll
        for (int nt = 0; nt < 8; ++nt)
          maxbf[(long)n * 128 + nt * 16 + m15] = (f16_t)0.f;
      }
    }
  };

  int n0 = nBeg - 1, c0 = -16, e0 = 0;
  adv(n0, c0, e0);
  if (n0 >= nEnd) return;

  f16x8 PnC[4], PnN[4];
#pragma unroll
  for (int kt = 0; kt < 4; ++kt)
    PnC[kt] = *(const f16x8*)(Pbuf + (long)n0 * 128 + kt * 32 + quad * 8);
  int r0 = srow[min(c0 + m15, e0 - 1)];

  int n1 = n0, c1 = c0, e1 = e0;
  adv(n1, c1, e1);

  f16x8 xv[4];
#pragma unroll
  for (int kt = 0; kt < 4; ++kt)
    xv[kt] = *(const f16x8*)(Abuf + (long)r0 * 128 + kt * 32 + quad * 8);

  int r1 = srow[min(c1 + m15, e1 - 1)];
#pragma unroll
  for (int kt = 0; kt < 4; ++kt) PnN[kt] = PnC[kt];
  if (n1 != n0 && n1 < nEnd) {
#pragma unroll
    for (int kt = 0; kt < 4; ++kt)
      PnN[kt] = *(const f16x8*)(Pbuf + (long)n1 * 128 + kt * 32 + quad * 8);
  }

  int n2 = n1, c2 = c1, e2 = e1;
  adv(n2, c2, e2);
  int r2 = srow[min(c2 + m15, e2 - 1)];

  float runmax[8];
#pragma unroll
  for (int nt = 0; nt < 8; ++nt) runmax[nt] = -3.4e38f;

  for (;;) {
    f16x8 xn[4];
#pragma unroll
    for (int kt = 0; kt < 4; ++kt)
      xn[kt] = *(const f16x8*)(Abuf + (long)r1 * 128 + kt * 32 + quad * 8);

#pragma unroll
    for (int kt = 0; kt < 4; ++kt) xv[kt] = sub_relu8(xv[kt], PnC[kt]);

#pragma unroll
    for (int half = 0; half < 2; ++half) {
      f32x4 a0 = (f32x4){0.f, 0.f, 0.f, 0.f}, a1 = a0, a2 = a0, a3 = a0;
#pragma unroll
      for (int kt = 0; kt < 4; ++kt) {
        a0 = __builtin_amdgcn_mfma_f32_16x16x32_f16(
            xv[kt], *(const f16x8*)&w2s[half * 4 + 0][kt][lane][0], a0, 0, 0, 0);
        a1 = __builtin_amdgcn_mfma_f32_16x16x32_f16(
            xv[kt], *(const f16x8*)&w2s[half * 4 + 1][kt][lane][0], a1, 0, 0, 0);
        a2 = __builtin_amdgcn_mfma_f32_16x16x32_f16(
            xv[kt], *(const f16x8*)&w2s[half * 4 + 2][kt][lane][0], a2, 0, 0, 0);
        a3 = __builtin_amdgcn_mfma_f32_16x16x32_f16(
            xv[kt], *(const f16x8*)&w2s[half * 4 + 3][kt][lane][0], a3, 0, 0, 0);
      }
      runmax[half * 4 + 0] = fmaxf(runmax[half * 4 + 0],
          fmaxf(fmaxf(a0[0], a0[1]), fmaxf(a0[2], a0[3])));
      runmax[half * 4 + 1] = fmaxf(runmax[half * 4 + 1],
          fmaxf(fmaxf(a1[0], a1[1]), fmaxf(a1[2], a1[3])));
      runmax[half * 4 + 2] = fmaxf(runmax[half * 4 + 2],
          fmaxf(fmaxf(a2[0], a2[1]), fmaxf(a2[2], a2[3])));
      runmax[half * 4 + 3] = fmaxf(runmax[half * 4 + 3],
          fmaxf(fmaxf(a3[0], a3[1]), fmaxf(a3[2], a3[3])));
    }

    if (n1 != n0) {
#pragma unroll
      for (int nt = 0; nt < 8; ++nt) {
        float v = runmax[nt];
        v = fmaxf(v, __shfl_xor(v, 16, 64));
        v = fmaxf(v, __shfl_xor(v, 32, 64));
        v += b2s[nt * 16 + m15];
        if (quad == 0) maxbf[(long)n0 * 128 + nt * 16 + m15] = (f16_t)v;
        runmax[nt] = -3.4e38f;
      }
#pragma unroll
      for (int kt = 0; kt < 4; ++kt) PnC[kt] = PnN[kt];
    }

    n0 = n1; c0 = c1; e0 = e1;
    if (n0 >= nEnd) break;
#pragma unroll
    for (int kt = 0; kt < 4; ++kt) xv[kt] = xn[kt];

    n1 = n2; c1 = c2; e1 = e2; r1 = r2;
    if (n1 != n0 && n1 < nEnd) {
#pragma unroll
      for (int kt = 0; kt < 4; ++kt)
        PnN[kt] = *(const f16x8*)(Pbuf + (long)n1 * 128 + kt * 32 + quad * 8);
    }

    adv(n2, c2, e2);
    r2 = srow[min(c2 + m15, e2 - 1)];
  }
}

// ---------------------------------------------------------------------------
// final: d_out = maxbf + x @ Wr + br   (f32 out)
// ---------------------------------------------------------------------------
__global__ __launch_bounds__(256) void final_gemm_kernel(
    const float* __restrict__ xin, const float* __restrict__ W,
    const float* __restrict__ bias, const f16_t* __restrict__ maxv,
    float* __restrict__ dst, int N)
{
  __shared__ f16_t ws_[8][4][64][8];
  __shared__ float bs_[128];

  const int tid = threadIdx.x;
  for (int it = tid; it < 8 * 4 * 64; it += 256) {
    int nt = it >> 8, kt = (it >> 6) & 3, l = it & 63;
    int n = nt * 16 + (l & 15), quad = l >> 4;
    f16x8 v;
#pragma unroll
    for (int j = 0; j < 8; ++j) v[j] = (f16_t)W[(kt * 32 + quad * 8 + j) * 128 + n];
    *(f16x8*)&ws_[nt][kt][l][0] = v;
  }
  if (tid < 128) bs_[tid] = bias[tid];
  __syncthreads();

  const int w = tid >> 6, lane = tid & 63;
  const int m15 = lane & 15, quad = lane >> 4;

  int node_a = blockIdx.x * 64 + w * 16 + m15;
  const float* xrow = xin + (long)min(node_a, N - 1) * 128;
  f16x8 a[4];
#pragma unroll
  for (int kt = 0; kt < 4; ++kt)
    a[kt] = load_frag8h(xrow + kt * 32 + quad * 8);

  f32x4 acc[8];
#pragma unroll
  for (int nt = 0; nt < 8; ++nt) acc[nt] = (f32x4){0.f, 0.f, 0.f, 0.f};
#pragma unroll
  for (int nt = 0; nt < 8; ++nt)
#pragma unroll
    for (int kt = 0; kt < 4; ++kt)
      acc[nt] = __builtin_amdgcn_mfma_f32_16x16x32_f16(
          a[kt], *(const f16x8*)&ws_[nt][kt][lane][0], acc[nt], 0, 0, 0);

#pragma unroll
  for (int r = 0; r < 4; ++r) {
    int node = blockIdx.x * 64 + w * 16 + quad * 4 + r;
    if (node < N) {
#pragma unroll
      for (int nt = 0; nt < 8; ++nt) {
        int c = nt * 16 + m15;
        long idx = (long)node * 128 + c;
        dst[idx] = acc[nt][r] + bs_[c] + (float)maxv[idx];
      }
    }
  }
}

extern "C" void kernel_launch(void* const* d_in, const int* in_sizes, int n_in,
                              void* d_out, int out_size, void* d_ws, size_t ws_size,
                              hipStream_t stream) {
  (void)n_in; (void)out_size;
  const float* x   = (const float*)d_in[0];
  const float* pos = (const float*)d_in[1];
  const int*   eix = (const int*)d_in[2];
  const float* W1  = (const float*)d_in[3];
  const float* b1  = (const float*)d_in[4];
  const float* W2  = (const float*)d_in[5];
  const float* b2  = (const float*)d_in[6];
  const float* Wr  = (const float*)d_in[7];
  const float* br  = (const float*)d_in[8];

  const int N = in_sizes[0] / 128;
  const int E = in_sizes[2] / 2;

  f16_t* Abuf = (f16_t*)d_out;                      // [0, N*128) f16
  f16_t* Pbuf = (f16_t*)d_out + (size_t)N * 128;    // [N*128, N*256) f16

  const int nodeBlocks = (N + 63) / 64;
  const int edgeBlocks = (E + 255) / 256;
  const int nTiles     = (N + 255) / 256;
  const int NSB        = (N + 255) >> NSB_SHIFT;
  const int paBlocks   = (E + PA_TILE - 1) / PA_TILE;

  f16_t* maxbf = (f16_t*)d_ws;                      // N*256 B

  // packed path ws: maxbf + pairsA + srow + start/end + superCursor
  const size_t needPack = (size_t)N * 256 + (size_t)NSB * SBCAP * 8 +
                          (size_t)N * 8 + (size_t)NSB * 64 + 1024;

  if (ws_size >= needPack && NSB <= 256 && N < (1 << 24)) {
    // ---------------- u32-bucketed CSR path ----------------
    unsigned* pairsA      = (unsigned*)((char*)d_ws + (size_t)N * 256);
    int*      srowN       = (int*)(pairsA + (size_t)NSB * SBCAP);
    int*      startB      = (int*)(srowN + (size_t)NSB * SBCAP);
    int*      endB        = startB + N;
    int*      superCursor = endB + N;

    hipMemsetAsync(superCursor, 0, (size_t)NSB * 64, stream);
    fusedA_kernel<<<nodeBlocks + paBlocks, 256, 0, stream>>>(
        x, pos, eix, W1, b1, pairsA, superCursor, Abuf, Pbuf, N, E, nodeBlocks);
    passb_kernel<<<NSB, 256, 0, stream>>>(pairsA, superCursor, srowN,
                                          startB, endB, N);
    pernode_kernel<<<2048, 256, 0, stream>>>(Abuf, Pbuf, W2, b2, startB, endB,
                                             srowN, maxbf, N);
  } else {
    // ---------------- fallback: r7 hist+scan+scatter ----------------
    int* srow  = (int*)((char*)d_ws + (size_t)N * 256);
    int* dpad  = srow + E;
    int* start = dpad + (size_t)N * DPAD;
    int* tsum  = start + N + 1;
    int* texcl = tsum + 256;

    hipMemsetAsync(dpad, 0, (size_t)N * DPAD * 4, stream);
    fused_hist_kernel<<<nodeBlocks + edgeBlocks, 256, 0, stream>>>(
        x, pos, eix, W1, b1, dpad, Abuf, Pbuf, N, E, nodeBlocks);
    tilesum_kernel<<<nTiles, 256, 0, stream>>>(dpad, tsum, N);
    tscan_kernel<<<1, 256, 0, stream>>>(tsum, texcl, &start[N], nTiles);
    scanout_kernel<<<nTiles, 256, 0, stream>>>(dpad, texcl, start, N);
    scatter_kernel<<<edgeBlocks, 256, 0, stream>>>(eix, dpad, srow, E);
    pernode_kernel<<<2048, 256, 0, stream>>>(Abuf, Pbuf, W2, b2, start, start + 1,
                                             srow, maxbf, N);
  }

  final_gemm_kernel<<<nodeBlocks, 256, 0, stream>>>(x, Wr, br, maxbf,
                                                    (float*)d_out, N);
}

// Round 6
// 267.398 us; speedup vs baseline: 2.7534x; 2.7534x over previous
//
#include <hip/hip_runtime.h>
#include <hip/hip_bf16.h>

// PointNetConv on MI355X (gfx950) — round 13. f32 inputs.
// Algebra: h1 = relu(A[row] - P[col]),  A = x@W1x + b1 + pos@W1p,  P = pos@W1p.
//
// r12 post-mortem: __launch_bounds__(256,4) on pernode crushed VGPR to 64 ->
// the 3-level pipeline (16 live f16x8 = 64 VGPR alone) spilled to scratch:
// FETCH 155MB -> 1.75GB, WRITE 12.5 -> 388MB, 664us. Occupancy rose to 38%
// and it was still 4x slower — spill-bought occupancy is worthless.
//
// r13: revert pernode to plain __launch_bounds__(256) (r10-proven config,
// 124 VGPR, zero spill). Keep r12's f16 packed relu + u32 passA + CSR passB,
// which now get their first clean measurement.

typedef _Float16 f16_t;
typedef _Float16 f16x8 __attribute__((ext_vector_type(8)));
typedef float    f32x4 __attribute__((ext_vector_type(4)));

#define DPAD 16
#define NSB_SHIFT 8          // 256 nodes per superbucket
#define SBCAP 9216           // per-bucket edge cap (mean 8192, +11 sigma)
#define PA_TILE 2048         // edges per passA tile

__device__ __forceinline__ f16x8 sub_relu8(f16x8 a, f16x8 b) {
  f16x8 d = a - b;                          // v_pk_add_f16 (neg)
  f16x8 z = {};
  return __builtin_elementwise_max(d, z);   // v_pk_max_f16
}

// ---------------- fallback scan chain (proven r7) ----------------
__global__ __launch_bounds__(256) void tilesum_kernel(const int* __restrict__ dpad,
                                                      int* __restrict__ tsum, int N) {
  __shared__ int ws[4];
  int tid = threadIdx.x;
  int i = blockIdx.x * 256 + tid;
  int v = (i < N) ? dpad[(long)i * DPAD] : 0;
#pragma unroll
  for (int off = 32; off > 0; off >>= 1) v += __shfl_down(v, off, 64);
  if ((tid & 63) == 0) ws[tid >> 6] = v;
  __syncthreads();
  if (tid == 0) tsum[blockIdx.x] = ws[0] + ws[1] + ws[2] + ws[3];
}

__global__ __launch_bounds__(256) void tscan_kernel(const int* __restrict__ tsum,
                                                    int* __restrict__ texcl,
                                                    int* __restrict__ startN, int nt_) {
  __shared__ int wsum[4];
  int tid = threadIdx.x, lane = tid & 63, w = tid >> 6;
  int v = (tid < nt_) ? tsum[tid] : 0;
  int s = v;
#pragma unroll
  for (int off = 1; off < 64; off <<= 1) {
    int t = __shfl_up(s, off, 64);
    if (lane >= off) s += t;
  }
  if (lane == 63) wsum[w] = s;
  __syncthreads();
  int add = 0;
  for (int j = 0; j < w; ++j) add += wsum[j];
  if (tid < nt_) texcl[tid] = add + s - v;
  if (tid == 0) *startN = wsum[0] + wsum[1] + wsum[2] + wsum[3];
}

__global__ __launch_bounds__(256) void scanout_kernel(int* __restrict__ dpad,
                                                      const int* __restrict__ texcl,
                                                      int* __restrict__ start, int N) {
  __shared__ int wsum[4];
  int tid = threadIdx.x, lane = tid & 63, w = tid >> 6;
  int i = blockIdx.x * 256 + tid;
  int v = (i < N) ? dpad[(long)i * DPAD] : 0;
  int s = v;
#pragma unroll
  for (int off = 1; off < 64; off <<= 1) {
    int t = __shfl_up(s, off, 64);
    if (lane >= off) s += t;
  }
  if (lane == 63) wsum[w] = s;
  __syncthreads();
  int add = texcl[blockIdx.x];
  for (int j = 0; j < w; ++j) add += wsum[j];
  int excl = add + s - v;
  if (i < N) { start[i] = excl; dpad[(long)i * DPAD + 8] = excl; }
}

__global__ __launch_bounds__(256) void scatter_kernel(const int* __restrict__ eidx,
                                                      int* __restrict__ dpad,
                                                      int* __restrict__ srow, int E) {
  int i = blockIdx.x * 256 + threadIdx.x;
  if (i < E) {
    int slot = atomicAdd(&dpad[(long)eidx[E + i] * DPAD + 8], 1);
    srow[slot] = eidx[i];
  }
}

__device__ __forceinline__ f16x8 load_frag8h(const float* p) {
  float4 a = *(const float4*)p;
  float4 b = *(const float4*)(p + 4);
  f16x8 r;
  r[0] = (f16_t)a.x; r[1] = (f16_t)a.y; r[2] = (f16_t)a.z; r[3] = (f16_t)a.w;
  r[4] = (f16_t)b.x; r[5] = (f16_t)b.y; r[6] = (f16_t)b.z; r[7] = (f16_t)b.w;
  return r;
}

// ---------------------------------------------------------------------------
// Shared-memory structs for the role-split kernels (union via char buffer).
// ---------------------------------------------------------------------------
struct GemmSmem {
  f16_t ws_[8][4][64][8];    // 32768 B
  float w1ps[3][128];        //  1536 B
  float bs_[128];            //   512 B
  float pos_s[64][3];        //   768 B
};                           // 35584 B

struct PassASmem {
  unsigned sorted[PA_TILE];       // 8192 B
  unsigned char sbb[PA_TILE];     // 2048 B
  int hist[256];
  int off_[256];
  int cur[256];
  int gbase[256];
  int scanb[256];
};                                // 15360 B

#define SMEM_BYTES 35840

// ---------------------------------------------------------------------------
// AP-GEMM body: A = x@W1x + b1 + pos@W1p, P = pos@W1p (f16 into d_out).
// ---------------------------------------------------------------------------
__device__ __forceinline__ void ap_gemm_body(
    const float* __restrict__ x, const float* __restrict__ pos,
    const float* __restrict__ W1, const float* __restrict__ b1,
    f16_t* __restrict__ Abuf, f16_t* __restrict__ Pbuf, int N, int blk,
    char* smem)
{
  GemmSmem* G = (GemmSmem*)smem;
  const int tid = threadIdx.x;
  for (int it = tid; it < 8 * 4 * 64; it += 256) {
    int nt = it >> 8, kt = (it >> 6) & 3, l = it & 63;
    int n = nt * 16 + (l & 15), quad = l >> 4;
    f16x8 v;
#pragma unroll
    for (int j = 0; j < 8; ++j) v[j] = (f16_t)W1[(kt * 32 + quad * 8 + j) * 128 + n];
    *(f16x8*)&G->ws_[nt][kt][l][0] = v;
  }
  for (int it = tid; it < 384; it += 256)
    G->w1ps[it >> 7][it & 127] = W1[(128 + (it >> 7)) * 128 + (it & 127)];
  if (tid < 128) G->bs_[tid] = b1[tid];
  {
    int g = blk * 192 + tid;
    if (tid < 192 && g < 3 * N) G->pos_s[tid / 3][tid % 3] = pos[g];
  }
  __syncthreads();

  const int w = tid >> 6, lane = tid & 63;
  const int m15 = lane & 15, quad = lane >> 4;

  int node_a = blk * 64 + w * 16 + m15;
  const float* xrow = x + (long)min(node_a, N - 1) * 128;
  f16x8 a[4];
#pragma unroll
  for (int kt = 0; kt < 4; ++kt)
    a[kt] = load_frag8h(xrow + kt * 32 + quad * 8);

  f32x4 acc[8];
#pragma unroll
  for (int nt = 0; nt < 8; ++nt) acc[nt] = (f32x4){0.f, 0.f, 0.f, 0.f};
#pragma unroll
  for (int nt = 0; nt < 8; ++nt)
#pragma unroll
    for (int kt = 0; kt < 4; ++kt)
      acc[nt] = __builtin_amdgcn_mfma_f32_16x16x32_f16(
          a[kt], *(const f16x8*)&G->ws_[nt][kt][lane][0], acc[nt], 0, 0, 0);

#pragma unroll
  for (int r = 0; r < 4; ++r) {
    int nl = w * 16 + quad * 4 + r;
    int node = blk * 64 + nl;
    if (node < N) {
      float p0 = G->pos_s[nl][0], p1 = G->pos_s[nl][1], p2 = G->pos_s[nl][2];
#pragma unroll
      for (int nt = 0; nt < 8; ++nt) {
        int c = nt * 16 + m15;
        float pv = p0 * G->w1ps[0][c] + p1 * G->w1ps[1][c] + p2 * G->w1ps[2][c];
        long idx = (long)node * 128 + c;
        Abuf[idx] = (f16_t)(acc[nt][r] + G->bs_[c] + pv);
        Pbuf[idx] = (f16_t)pv;
      }
    }
  }
}

// ---------------------------------------------------------------------------
// passA body: tile-sort PA_TILE edges into superbuckets, all random ops in
// LDS; ~NSB aggregated global atomics per tile; coalesced u32 segment writes.
// Entry format: (col&255)<<24 | row.
// ---------------------------------------------------------------------------
__device__ __forceinline__ void passa_body(
    const int* __restrict__ eidx, unsigned* __restrict__ pairsBuf,
    int* __restrict__ superCursor, int E, int tile, char* smem)
{
  PassASmem* S = (PassASmem*)smem;
  const int tid = threadIdx.x;
  const int base = tile * PA_TILE;
  const int cnt_t = min(PA_TILE, E - base);

  for (int j = tid; j < 256; j += 256) S->hist[j] = 0;
  __syncthreads();

  int myrow[8], mycol[8];
#pragma unroll
  for (int k = 0; k < 8; ++k) {
    int idx = k * 256 + tid;
    int i = base + idx;
    if (idx < cnt_t) {
      myrow[k] = eidx[i];
      mycol[k] = eidx[E + i];
      atomicAdd(&S->hist[mycol[k] >> NSB_SHIFT], 1);
    } else mycol[k] = -1;
  }
  __syncthreads();

  int v = S->hist[tid];
  S->scanb[tid] = v;
  __syncthreads();
  for (int d = 1; d < 256; d <<= 1) {
    int t = (tid >= d) ? S->scanb[tid - d] : 0;
    __syncthreads();
    S->scanb[tid] += t;
    __syncthreads();
  }
  int excl = S->scanb[tid] - v;
  S->off_[tid] = excl;
  S->cur[tid]  = excl;
  S->gbase[tid] = (v > 0) ? atomicAdd(&superCursor[tid * 16], v) : 0;
  __syncthreads();

#pragma unroll
  for (int k = 0; k < 8; ++k) {
    if (mycol[k] >= 0) {
      int sb = mycol[k] >> NSB_SHIFT;
      int pos = atomicAdd(&S->cur[sb], 1);
      S->sorted[pos] = ((unsigned)(mycol[k] & 255) << 24) | (unsigned)myrow[k];
      S->sbb[pos] = (unsigned char)sb;
    }
  }
  __syncthreads();

#pragma unroll
  for (int k = 0; k < 8; ++k) {
    int idx = k * 256 + tid;
    if (idx < cnt_t) {
      int sb = S->sbb[idx];
      int local = idx - S->off_[sb];
      int g = S->gbase[sb] + local;
      if (g < SBCAP) pairsBuf[(long)sb * SBCAP + g] = S->sorted[idx];
    }
  }
}

// fusedA: AP-GEMM role + passA role in one launch (overlap).
__global__ __launch_bounds__(256) void fusedA_kernel(
    const float* __restrict__ x, const float* __restrict__ pos,
    const int* __restrict__ eidx, const float* __restrict__ W1,
    const float* __restrict__ b1, unsigned* __restrict__ pairsBuf,
    int* __restrict__ superCursor, f16_t* __restrict__ Abuf,
    f16_t* __restrict__ Pbuf, int N, int E, int nodeBlocks)
{
  __shared__ __align__(16) char smem[SMEM_BYTES];
  if ((int)blockIdx.x >= nodeBlocks) {
    passa_body(eidx, pairsBuf, superCursor, E, (int)blockIdx.x - nodeBlocks, smem);
    return;
  }
  ap_gemm_body(x, pos, W1, b1, Abuf, Pbuf, N, blockIdx.x, smem);
}

// Fallback path: hist role + AP-GEMM role (r7-proven).
__global__ __launch_bounds__(256) void fused_hist_kernel(
    const float* __restrict__ x, const float* __restrict__ pos,
    const int* __restrict__ eidx, const float* __restrict__ W1,
    const float* __restrict__ b1, int* __restrict__ dpad,
    f16_t* __restrict__ Abuf, f16_t* __restrict__ Pbuf,
    int N, int E, int nodeBlocks)
{
  __shared__ __align__(16) char smem[SMEM_BYTES];
  if ((int)blockIdx.x >= nodeBlocks) {
    int i = ((int)blockIdx.x - nodeBlocks) * 256 + threadIdx.x;
    if (i < E) atomicAdd(&dpad[(long)eidx[E + i] * DPAD], 1);
    return;
  }
  ap_gemm_body(x, pos, W1, b1, Abuf, Pbuf, N, blockIdx.x, smem);
}

// ---------------------------------------------------------------------------
// passB: one block per superbucket; exact per-node CSR built in LDS from u32
// pairs. Emits r10-format CSR: srow (row indices), startB[n], endB[n].
// ---------------------------------------------------------------------------
__global__ __launch_bounds__(256) void passb_kernel(
    const unsigned* __restrict__ pairsA, const int* __restrict__ superCursor,
    int* __restrict__ srow, int* __restrict__ startB, int* __restrict__ endB,
    int N)
{
  __shared__ int rows[SBCAP];     // 36 KB
  __shared__ int deg[256], scanb[256], cur[256];
  const int sb = blockIdx.x, tid = threadIdx.x;
  const int cntIn = min(superCursor[sb * 16], SBCAP);
  const unsigned* Pin = pairsA + (long)sb * SBCAP;

  deg[tid] = 0;
  __syncthreads();
  for (int i = tid; i < cntIn; i += 256)
    atomicAdd(&deg[Pin[i] >> 24], 1);
  __syncthreads();
  int d = deg[tid];
  scanb[tid] = d;
  __syncthreads();
  for (int s = 1; s < 256; s <<= 1) {
    int t2 = (tid >= s) ? scanb[tid - s] : 0;
    __syncthreads();
    scanb[tid] += t2;
    __syncthreads();
  }
  int excl = scanb[tid] - d;
  cur[tid] = excl;
  int n = (sb << NSB_SHIFT) + tid;
  if (n < N) {
    startB[n] = sb * SBCAP + excl;
    endB[n]   = sb * SBCAP + excl + d;
  }
  __syncthreads();
  for (int i = tid; i < cntIn; i += 256) {
    unsigned p = Pin[i];
    int slot = atomicAdd(&cur[p >> 24], 1);
    rows[slot] = (int)(p & 0xFFFFFFu);
  }
  __syncthreads();
  const int gb = sb * SBCAP;
  for (int i = tid; i < cntIn; i += 256) srow[gb + i] = rows[i];
}

// ---------------------------------------------------------------------------
// pernode (r10-proven structure, f16 packed): continuous (node,chunk) stream
// per wave over a contiguous node range; 3-level pipeline crossing node
// boundaries (srow 2 ahead, A-gather + next-node P 1 ahead, compute level-0).
// Plain __launch_bounds__(256): r12's (256,4) crushed VGPR to 64 and spilled.
// ---------------------------------------------------------------------------
__global__ __launch_bounds__(256) void pernode_kernel(
    const f16_t* __restrict__ Abuf, const f16_t* __restrict__ Pbuf,
    const float* __restrict__ W2, const float* __restrict__ b2,
    const int* __restrict__ startp, const int* __restrict__ endp,
    const int* __restrict__ srow, f16_t* __restrict__ maxbf, int N)
{
  __shared__ f16_t w2s[8][4][64][8];   // 32 KB, B-fragment-major
  __shared__ float b2s[128];

  const int tid = threadIdx.x;
  for (int it = tid; it < 8 * 4 * 64; it += 256) {
    int nt = it >> 8, kt = (it >> 6) & 3, l = it & 63;
    int ncol = nt * 16 + (l & 15), q = l >> 4;
    f16x8 v;
#pragma unroll
    for (int j = 0; j < 8; ++j) v[j] = (f16_t)W2[(kt * 32 + q * 8 + j) * 128 + ncol];
    *(f16x8*)&w2s[nt][kt][l][0] = v;
  }
  if (tid < 128) b2s[tid] = b2[tid];
  __syncthreads();

  const int w = tid >> 6, lane = tid & 63;
  const int m15 = lane & 15, quad = lane >> 4;

  const int nslots = (int)gridDim.x * 4;
  const int slot   = (int)blockIdx.x * 4 + w;
  const int K      = (N + nslots - 1) / nslots;
  const int nBeg   = slot * K;
  const int nEnd   = min(N, nBeg + K);
  if (nBeg >= nEnd) return;

  auto adv = [&](int& n, int& c, int& e) {
    c += 16;
    if (c < e) return;
    for (;;) {
      if (++n >= nEnd) { n = nEnd; c -= 16; return; }
      int s_ = startp[n], e_ = endp[n];
      if (e_ > s_) { c = s_; e = e_; return; }
      if (quad == 0) {
#pragma unroll
        for (int nt = 0; nt < 8; ++nt)
          maxbf[(long)n * 128 + nt * 16 + m15] = (f16_t)0.f;
      }
    }
  };

  int n0 = nBeg - 1, c0 = -16, e0 = 0;
  adv(n0, c0, e0);
  if (n0 >= nEnd) return;

  f16x8 PnC[4], PnN[4];
#pragma unroll
  for (int kt = 0; kt < 4; ++kt)
    PnC[kt] = *(const f16x8*)(Pbuf + (long)n0 * 128 + kt * 32 + quad * 8);
  int r0 = srow[min(c0 + m15, e0 - 1)];

  int n1 = n0, c1 = c0, e1 = e0;
  adv(n1, c1, e1);

  f16x8 xv[4];
#pragma unroll
  for (int kt = 0; kt < 4; ++kt)
    xv[kt] = *(const f16x8*)(Abuf + (long)r0 * 128 + kt * 32 + quad * 8);

  int r1 = srow[min(c1 + m15, e1 - 1)];
#pragma unroll
  for (int kt = 0; kt < 4; ++kt) PnN[kt] = PnC[kt];
  if (n1 != n0 && n1 < nEnd) {
#pragma unroll
    for (int kt = 0; kt < 4; ++kt)
      PnN[kt] = *(const f16x8*)(Pbuf + (long)n1 * 128 + kt * 32 + quad * 8);
  }

  int n2 = n1, c2 = c1, e2 = e1;
  adv(n2, c2, e2);
  int r2 = srow[min(c2 + m15, e2 - 1)];

  float runmax[8];
#pragma unroll
  for (int nt = 0; nt < 8; ++nt) runmax[nt] = -3.4e38f;

  for (;;) {
    f16x8 xn[4];
#pragma unroll
    for (int kt = 0; kt < 4; ++kt)
      xn[kt] = *(const f16x8*)(Abuf + (long)r1 * 128 + kt * 32 + quad * 8);

#pragma unroll
    for (int kt = 0; kt < 4; ++kt) xv[kt] = sub_relu8(xv[kt], PnC[kt]);

#pragma unroll
    for (int half = 0; half < 2; ++half) {
      f32x4 a0 = (f32x4){0.f, 0.f, 0.f, 0.f}, a1 = a0, a2 = a0, a3 = a0;
#pragma unroll
      for (int kt = 0; kt < 4; ++kt) {
        a0 = __builtin_amdgcn_mfma_f32_16x16x32_f16(
            xv[kt], *(const f16x8*)&w2s[half * 4 + 0][kt][lane][0], a0, 0, 0, 0);
        a1 = __builtin_amdgcn_mfma_f32_16x16x32_f16(
            xv[kt], *(const f16x8*)&w2s[half * 4 + 1][kt][lane][0], a1, 0, 0, 0);
        a2 = __builtin_amdgcn_mfma_f32_16x16x32_f16(
            xv[kt], *(const f16x8*)&w2s[half * 4 + 2][kt][lane][0], a2, 0, 0, 0);
        a3 = __builtin_amdgcn_mfma_f32_16x16x32_f16(
            xv[kt], *(const f16x8*)&w2s[half * 4 + 3][kt][lane][0], a3, 0, 0, 0);
      }
      runmax[half * 4 + 0] = fmaxf(runmax[half * 4 + 0],
          fmaxf(fmaxf(a0[0], a0[1]), fmaxf(a0[2], a0[3])));
      runmax[half * 4 + 1] = fmaxf(runmax[half * 4 + 1],
          fmaxf(fmaxf(a1[0], a1[1]), fmaxf(a1[2], a1[3])));
      runmax[half * 4 + 2] = fmaxf(runmax[half * 4 + 2],
          fmaxf(fmaxf(a2[0], a2[1]), fmaxf(a2[2], a2[3])));
      runmax[half * 4 + 3] = fmaxf(runmax[half * 4 + 3],
          fmaxf(fmaxf(a3[0], a3[1]), fmaxf(a3[2], a3[3])));
    }

    if (n1 != n0) {
#pragma unroll
      for (int nt = 0; nt < 8; ++nt) {
        float v = runmax[nt];
        v = fmaxf(v, __shfl_xor(v, 16, 64));
        v = fmaxf(v, __shfl_xor(v, 32, 64));
        v += b2s[nt * 16 + m15];
        if (quad == 0) maxbf[(long)n0 * 128 + nt * 16 + m15] = (f16_t)v;
        runmax[nt] = -3.4e38f;
      }
#pragma unroll
      for (int kt = 0; kt < 4; ++kt) PnC[kt] = PnN[kt];
    }

    n0 = n1; c0 = c1; e0 = e1;
    if (n0 >= nEnd) break;
#pragma unroll
    for (int kt = 0; kt < 4; ++kt) xv[kt] = xn[kt];

    n1 = n2; c1 = c2; e1 = e2; r1 = r2;
    if (n1 != n0 && n1 < nEnd) {
#pragma unroll
      for (int kt = 0; kt < 4; ++kt)
        PnN[kt] = *(const f16x8*)(Pbuf + (long)n1 * 128 + kt * 32 + quad * 8);
    }

    adv(n2, c2, e2);
    r2 = srow[min(c2 + m15, e2 - 1)];
  }
}

// ---------------------------------------------------------------------------
// final: d_out = maxbf + x @ Wr + br   (f32 out)
// ---------------------------------------------------------------------------
__global__ __launch_bounds__(256) void final_gemm_kernel(
    const float* __restrict__ xin, const float* __restrict__ W,
    const float* __restrict__ bias, const f16_t* __restrict__ maxv,
    float* __restrict__ dst, int N)
{
  __shared__ f16_t ws_[8][4][64][8];
  __shared__ float bs_[128];

  const int tid = threadIdx.x;
  for (int it = tid; it < 8 * 4 * 64; it += 256) {
    int nt = it >> 8, kt = (it >> 6) & 3, l = it & 63;
    int n = nt * 16 + (l & 15), quad = l >> 4;
    f16x8 v;
#pragma unroll
    for (int j = 0; j < 8; ++j) v[j] = (f16_t)W[(kt * 32 + quad * 8 + j) * 128 + n];
    *(f16x8*)&ws_[nt][kt][l][0] = v;
  }
  if (tid < 128) bs_[tid] = bias[tid];
  __syncthreads();

  const int w = tid >> 6, lane = tid & 63;
  const int m15 = lane & 15, quad = lane >> 4;

  int node_a = blockIdx.x * 64 + w * 16 + m15;
  const float* xrow = xin + (long)min(node_a, N - 1) * 128;
  f16x8 a[4];
#pragma unroll
  for (int kt = 0; kt < 4; ++kt)
    a[kt] = load_frag8h(xrow + kt * 32 + quad * 8);

  f32x4 acc[8];
#pragma unroll
  for (int nt = 0; nt < 8; ++nt) acc[nt] = (f32x4){0.f, 0.f, 0.f, 0.f};
#pragma unroll
  for (int nt = 0; nt < 8; ++nt)
#pragma unroll
    for (int kt = 0; kt < 4; ++kt)
      acc[nt] = __builtin_amdgcn_mfma_f32_16x16x32_f16(
          a[kt], *(const f16x8*)&ws_[nt][kt][lane][0], acc[nt], 0, 0, 0);

#pragma unroll
  for (int r = 0; r < 4; ++r) {
    int node = blockIdx.x * 64 + w * 16 + quad * 4 + r;
    if (node < N) {
#pragma unroll
      for (int nt = 0; nt < 8; ++nt) {
        int c = nt * 16 + m15;
        long idx = (long)node * 128 + c;
        dst[idx] = acc[nt][r] + bs_[c] + (float)maxv[idx];
      }
    }
  }
}

extern "C" void kernel_launch(void* const* d_in, const int* in_sizes, int n_in,
                              void* d_out, int out_size, void* d_ws, size_t ws_size,
                              hipStream_t stream) {
  (void)n_in; (void)out_size;
  const float* x   = (const float*)d_in[0];
  const float* pos = (const float*)d_in[1];
  const int*   eix = (const int*)d_in[2];
  const float* W1  = (const float*)d_in[3];
  const float* b1  = (const float*)d_in[4];
  const float* W2  = (const float*)d_in[5];
  const float* b2  = (const float*)d_in[6];
  const float* Wr  = (const float*)d_in[7];
  const float* br  = (const float*)d_in[8];

  const int N = in_sizes[0] / 128;
  const int E = in_sizes[2] / 2;

  f16_t* Abuf = (f16_t*)d_out;                      // [0, N*128) f16
  f16_t* Pbuf = (f16_t*)d_out + (size_t)N * 128;    // [N*128, N*256) f16

  const int nodeBlocks = (N + 63) / 64;
  const int edgeBlocks = (E + 255) / 256;
  const int nTiles     = (N + 255) / 256;
  const int NSB        = (N + 255) >> NSB_SHIFT;
  const int paBlocks   = (E + PA_TILE - 1) / PA_TILE;

  f16_t* maxbf = (f16_t*)d_ws;                      // N*256 B

  // packed path ws: maxbf + pairsA + srow + start/end + superCursor
  const size_t needPack = (size_t)N * 256 + (size_t)NSB * SBCAP * 8 +
                          (size_t)N * 8 + (size_t)NSB * 64 + 1024;

  if (ws_size >= needPack && NSB <= 256 && N < (1 << 24)) {
    // ---------------- u32-bucketed CSR path ----------------
    unsigned* pairsA      = (unsigned*)((char*)d_ws + (size_t)N * 256);
    int*      srowN       = (int*)(pairsA + (size_t)NSB * SBCAP);
    int*      startB      = (int*)(srowN + (size_t)NSB * SBCAP);
    int*      endB        = startB + N;
    int*      superCursor = endB + N;

    hipMemsetAsync(superCursor, 0, (size_t)NSB * 64, stream);
    fusedA_kernel<<<nodeBlocks + paBlocks, 256, 0, stream>>>(
        x, pos, eix, W1, b1, pairsA, superCursor, Abuf, Pbuf, N, E, nodeBlocks);
    passb_kernel<<<NSB, 256, 0, stream>>>(pairsA, superCursor, srowN,
                                          startB, endB, N);
    pernode_kernel<<<2048, 256, 0, stream>>>(Abuf, Pbuf, W2, b2, startB, endB,
                                             srowN, maxbf, N);
  } else {
    // ---------------- fallback: r7 hist+scan+scatter ----------------
    int* srow  = (int*)((char*)d_ws + (size_t)N * 256);
    int* dpad  = srow + E;
    int* start = dpad + (size_t)N * DPAD;
    int* tsum  = start + N + 1;
    int* texcl = tsum + 256;

    hipMemsetAsync(dpad, 0, (size_t)N * DPAD * 4, stream);
    fused_hist_kernel<<<nodeBlocks + edgeBlocks, 256, 0, stream>>>(
        x, pos, eix, W1, b1, dpad, Abuf, Pbuf, N, E, nodeBlocks);
    tilesum_kernel<<<nTiles, 256, 0, stream>>>(dpad, tsum, N);
    tscan_kernel<<<1, 256, 0, stream>>>(tsum, texcl, &start[N], nTiles);
    scanout_kernel<<<nTiles, 256, 0, stream>>>(dpad, texcl, start, N);
    scatter_kernel<<<edgeBlocks, 256, 0, stream>>>(eix, dpad, srow, E);
    pernode_kernel<<<2048, 256, 0, stream>>>(Abuf, Pbuf, W2, b2, start, start + 1,
                                             srow, maxbf, N);
  }

  final_gemm_kernel<<<nodeBlocks, 256, 0, stream>>>(x, Wr, br, maxbf,
                                                    (float*)d_out, N);
}